// Round 16
// baseline (138.234 us; speedup 1.0000x reference)
//
#include <hip/hip_runtime.h>
#include <math.h>

#define NN 30000
#define EE 480000
#define NEG_SLOPE 0.2f
#define LDK 136          // gemm1 LDS K-stride (bf16 elems)
#define LDK2 264         // gemm2 LDS K-stride (bf16 elems)
#define CAP 48           // fixed bucket capacity per node (deg max ~40 << 47)
#define NPB 1875         // scatter blocks (= bn partial count)
#define NGB 938          // gemm1 blocks (ceil(NN/32))
#define EAQ 32767.0f
#define LN2V 0.6931472f

// ---------------- workspace layout (float units)
static const size_t I_FILL  = 0;          // NN ints
static const size_t F_PART  = 30000;      // 4096
static const size_t F_SCAL  = 34096;      // 16
static const size_t F_WTB   = 34112;      // W1^T bf16 [256][128]
static const size_t F_WT2B  = 50496;      // W2^T bf16 [32][256]
static const size_t F_HB    = 54592;      // NN*256 ushorts (bf16 h)
static const size_t F_S1    = 3894592;    // NN*4
static const size_t F_D1    = 4014592;    // NN*4
static const size_t F_H1B   = 4134592;    // NN*256 ushorts (bf16 h1)
static const size_t F_H2    = 7974592;    // NN*32
static const size_t F_S2    = 8934592;    // NN
static const size_t F_D2    = 8964592;    // NN
static const size_t I_ER    = 8994592;    // NN*48 uint (src<<15 | ea_q15)

typedef __attribute__((ext_vector_type(4))) float f32x4;
typedef __attribute__((ext_vector_type(8))) short bf16x8;

__device__ __forceinline__ float wsum64(float v) {
    #pragma unroll
    for (int o = 32; o; o >>= 1) v += __shfl_xor(v, o);
    return v;
}
__device__ __forceinline__ unsigned int pack_bf2(float a, float b) {
    unsigned int ua = __float_as_uint(a);
    unsigned int ub = __float_as_uint(b);
    ua = (ua + 0x7FFFu + ((ua >> 16) & 1u)) >> 16;
    ub = (ub + 0x7FFFu + ((ub >> 16) & 1u)) & 0xFFFF0000u;
    return ua | ub;
}
__device__ __forceinline__ unsigned short bf16r(float f) {
    unsigned int u = __float_as_uint(f);
    u = (u + 0x7FFFu + ((u >> 16) & 1u)) >> 16;
    return (unsigned short)u;
}
__device__ __forceinline__ float bflo(unsigned int u) { return __uint_as_float(u << 16); }
__device__ __forceinline__ float bfhi(unsigned int u) { return __uint_as_float(u & 0xFFFF0000u); }

// ---- K0: convert/transpose W1/W2 to bf16 + zero fill ------------------------
__global__ __launch_bounds__(256) void k_prepw(const float* __restrict__ W1,
        const float* __restrict__ W2, unsigned short* __restrict__ wtb,
        unsigned short* __restrict__ wt2b, int* __restrict__ fill) {
    int idx = blockIdx.x * 256 + threadIdx.x;
    if (idx < NN) fill[idx] = 0;
    if (idx < 128 * 256) {
        int k = idx >> 8, n = idx & 255;
        wtb[n * 128 + k] = bf16r(W1[idx]);
    } else if (idx < 128 * 256 + 256 * 32) {
        int i2 = idx - 128 * 256;
        int k = i2 >> 5, c = i2 & 31;
        wt2b[c * 256 + k] = bf16r(W2[i2]);
    }
}

// ---- K1: FUSED scatter (blocks [0,NPB)) || gemm1 (blocks [NPB,NPB+NGB)) -----
// Scatter: 4-byte packed records (src<<15 | ea_q15) -> 48-slot buckets + BN sums
// Gemm1:   h = x @ W1 MFMA bf16 -> hb + fused s1/d1; B read from L2 wtb.
__global__ __launch_bounds__(256) void k_scat_gemm(const int* __restrict__ src,
        const int* __restrict__ dst, const float* __restrict__ eattr,
        int* __restrict__ fill, unsigned int* __restrict__ er,
        float* __restrict__ part,
        const float* __restrict__ x, const unsigned short* __restrict__ wtb,
        const float* __restrict__ as1, const float* __restrict__ ad1,
        unsigned short* __restrict__ hb, float* __restrict__ s1,
        float* __restrict__ d1, int E, int M) {
    __shared__ char shbuf[32 * LDK * 2];   // 8704 B, shared by both paths
    int tid = threadIdx.x;

    if (blockIdx.x < NPB) {
        // ================= scatter path =================
        float* sa = (float*)shbuf;
        float* sb = sa + 256;
        int e = blockIdx.x * 256 + tid;
        float s = 0.f, s2 = 0.f;
        if (e < E) {
            float lv = log1pf(eattr[e]);
            s = lv; s2 = lv * lv;
            int d = dst[e];
            int pos = atomicAdd(&fill[d], 1);
            if (pos > CAP - 2) pos = CAP - 2;   // safety clamp
            unsigned int q = (unsigned int)(lv * (EAQ / LN2V) + 0.5f);
            if (q > 32767u) q = 32767u;
            er[d * CAP + pos] = ((unsigned int)src[e] << 15) | q;
        }
        sa[tid] = s; sb[tid] = s2;
        __syncthreads();
        for (int o = 128; o; o >>= 1) {
            if (tid < o) { sa[tid] += sa[tid + o]; sb[tid] += sb[tid + o]; }
            __syncthreads();
        }
        if (tid == 0) { part[blockIdx.x * 2] = sa[0]; part[blockIdx.x * 2 + 1] = sb[0]; }
        return;
    }

    // ================= gemm1 path =================
    unsigned short* xs = (unsigned short*)shbuf;    // 32 x LDK bf16
    int bm = (blockIdx.x - NPB) * 32;
    #pragma unroll
    for (int i = 0; i < 4; i++) {
        int idx = tid + i * 256;
        int row = idx >> 5, c4 = (idx & 31) * 4;
        int grow = bm + row;
        float4 v = make_float4(0.f, 0.f, 0.f, 0.f);
        if (grow < M) v = *(const float4*)&x[grow * 128 + c4];
        uint2 p = make_uint2(pack_bf2(v.x, v.y), pack_bf2(v.z, v.w));
        *(uint2*)&xs[row * LDK + c4] = p;
    }
    __syncthreads();

    int w = tid >> 6;
    int l = tid & 63;
    int l15 = l & 15, lg = l >> 4;

    f32x4 acc[2][4];
    #pragma unroll
    for (int m = 0; m < 2; m++)
        #pragma unroll
        for (int n = 0; n < 4; n++) acc[m][n] = (f32x4){0.f, 0.f, 0.f, 0.f};

    #pragma unroll
    for (int ks = 0; ks < 4; ks++) {
        int k0 = ks * 32 + lg * 8;
        bf16x8 a0 = *(const bf16x8*)&xs[(l15) * LDK + k0];
        bf16x8 a1 = *(const bf16x8*)&xs[(16 + l15) * LDK + k0];
        bf16x8 b[4];
        #pragma unroll
        for (int n = 0; n < 4; n++)
            b[n] = *(const bf16x8*)&wtb[(w * 64 + n * 16 + l15) * 128 + k0];
        #pragma unroll
        for (int n = 0; n < 4; n++) {
            acc[0][n] = __builtin_amdgcn_mfma_f32_16x16x32_bf16(a0, b[n], acc[0][n], 0, 0, 0);
            acc[1][n] = __builtin_amdgcn_mfma_f32_16x16x32_bf16(a1, b[n], acc[1][n], 0, 0, 0);
        }
    }

    #pragma unroll
    for (int m = 0; m < 2; m++) {
        #pragma unroll
        for (int r = 0; r < 4; r++) {
            int grow = bm + m * 16 + lg * 4 + r;
            if (grow < M) {
                #pragma unroll
                for (int n = 0; n < 4; n++)
                    hb[grow * 256 + w * 64 + n * 16 + l15] = bf16r(acc[m][n][r]);
            }
        }
    }
    float as_c[4], ad_c[4];
    #pragma unroll
    for (int n = 0; n < 4; n++) {
        as_c[n] = as1[w * 64 + n * 16 + l15];
        ad_c[n] = ad1[w * 64 + n * 16 + l15];
    }
    float sp[2][4], dp[2][4];
    #pragma unroll
    for (int m = 0; m < 2; m++)
        #pragma unroll
        for (int r = 0; r < 4; r++) {
            float s = 0.f, d = 0.f;
            #pragma unroll
            for (int n = 0; n < 4; n++) {
                s += acc[m][n][r] * as_c[n];
                d += acc[m][n][r] * ad_c[n];
            }
            sp[m][r] = s; dp[m][r] = d;
        }
    #pragma unroll
    for (int o = 1; o < 16; o <<= 1) {
        #pragma unroll
        for (int m = 0; m < 2; m++)
            #pragma unroll
            for (int r = 0; r < 4; r++) {
                sp[m][r] += __shfl_xor(sp[m][r], o);
                dp[m][r] += __shfl_xor(dp[m][r], o);
            }
    }
    if (l15 == 0) {
        #pragma unroll
        for (int m = 0; m < 2; m++)
            #pragma unroll
            for (int r = 0; r < 4; r++) {
                int grow = bm + m * 16 + lg * 4 + r;
                if (grow < M) {
                    s1[grow * 4 + w] = sp[m][r];
                    d1[grow * 4 + w] = dp[m][r];
                }
            }
    }
}

// ---- K2: finalize BN + folded attention edge constants ----------------------
// scal[4..7] = kA*ce1_h   scal[10..13] = kB*ce1_h
// scal[8]    = kA*ce2     scal[9]      = kB*ce2
__global__ __launch_bounds__(512) void k_bn_final(const float* __restrict__ part,
        const float* __restrict__ gamma, const float* __restrict__ beta,
        const float* __restrict__ We1, const float* __restrict__ ae1,
        const float* __restrict__ We2, const float* __restrict__ ae2,
        float* __restrict__ scal, int E) {
    __shared__ float sa[512], sb[512], sc[256];
    int tid = threadIdx.x;
    float s = 0.f, s2 = 0.f;
    for (int i = tid; i < NPB; i += 512) {
        s += part[2 * i]; s2 += part[2 * i + 1];
    }
    sa[tid] = s; sb[tid] = s2;
    if (tid < 256) sc[tid] = We1[tid] * ae1[tid];
    __syncthreads();
    for (int o = 256; o; o >>= 1) {
        if (tid < o) { sa[tid] += sa[tid + o]; sb[tid] += sb[tid + o]; }
        __syncthreads();
    }
    if (tid == 0) {
        float mu = sa[0] / (float)E;
        float var = sb[0] / (float)E - mu * mu;
        float kA = gamma[0] / sqrtf(var + 1e-5f);
        float kB = beta[0] - mu * kA;
        for (int h = 0; h < 4; h++) {
            float s1 = 0.f;
            for (int d = 0; d < 64; d++) s1 += sc[h * 64 + d];
            scal[4 + h] = kA * s1;
            scal[10 + h] = kB * s1;
        }
        float s22 = 0.f;
        for (int d = 0; d < 32; d++) s22 += We2[d] * ae2[d];
        scal[8] = kA * s22;
        scal[9] = kB * s22;
    }
}

// ------- K3: FUSED layer-1 attention + aggregation ---------------------------
__global__ __launch_bounds__(256) void k_agg1(const int* __restrict__ fill,
        const unsigned int* __restrict__ er, const float* __restrict__ s1,
        const float* __restrict__ d1, const float* __restrict__ scal,
        const unsigned short* __restrict__ hb, const float* __restrict__ b1,
        unsigned short* __restrict__ h1b, int N) {
    __shared__ float sma[4][256];   // per-wave alpha table [edge][head]
    __shared__ int   sms[4][64];    // per-wave src table
    int wid = threadIdx.x >> 6;
    int node = blockIdx.x * 4 + wid;
    if (node >= N) return;
    int lane = threadIdx.x & 63;
    int deg = fill[node]; if (deg > CAP - 1) deg = CAP - 1;
    float4 dv = *(const float4*)&d1[node * 4];
    float4 ce = *(const float4*)&scal[4];
    float4 cc = *(const float4*)&scal[10];

    // load packed record; lane >= deg defaults to (node, 0)
    unsigned int rec = (unsigned int)node << 15;
    if (lane < deg) rec = er[node * CAP + lane];
    unsigned int sidx = rec >> 15;
    float ev = (float)(rec & 32767u) * (LN2V / EAQ);
    if (lane >= deg) ev = 0.f;
    float evm = wsum64(ev) / fmaxf((float)deg, 1.f);   // self-loop raw mean
    int degT = deg + 1;
    if (lane == deg) ev = evm;
    bool valid = lane < degT;

    float4 l = make_float4(-1e30f, -1e30f, -1e30f, -1e30f);
    if (valid) {
        float4 sv = *(const float4*)&s1[sidx * 4];
        l.x = sv.x + dv.x + ev * ce.x + cc.x;
        l.y = sv.y + dv.y + ev * ce.y + cc.y;
        l.z = sv.z + dv.z + ev * ce.z + cc.z;
        l.w = sv.w + dv.w + ev * ce.w + cc.w;
        l.x = l.x > 0.f ? l.x : NEG_SLOPE * l.x;
        l.y = l.y > 0.f ? l.y : NEG_SLOPE * l.y;
        l.z = l.z > 0.f ? l.z : NEG_SLOPE * l.z;
        l.w = l.w > 0.f ? l.w : NEG_SLOPE * l.w;
    }
    float4 mx = l;
    #pragma unroll
    for (int o = 32; o; o >>= 1) {
        mx.x = fmaxf(mx.x, __shfl_xor(mx.x, o));
        mx.y = fmaxf(mx.y, __shfl_xor(mx.y, o));
        mx.z = fmaxf(mx.z, __shfl_xor(mx.z, o));
        mx.w = fmaxf(mx.w, __shfl_xor(mx.w, o));
    }
    float4 ex = make_float4(0.f, 0.f, 0.f, 0.f);
    if (valid) {
        ex.x = __expf(l.x - mx.x); ex.y = __expf(l.y - mx.y);
        ex.z = __expf(l.z - mx.z); ex.w = __expf(l.w - mx.w);
    }
    float4 sm = ex;
    #pragma unroll
    for (int o = 32; o; o >>= 1) {
        sm.x += __shfl_xor(sm.x, o); sm.y += __shfl_xor(sm.y, o);
        sm.z += __shfl_xor(sm.z, o); sm.w += __shfl_xor(sm.w, o);
    }
    // publish (alpha, src) to wave-private LDS (zeros for invalid)
    *(float4*)&sma[wid][lane * 4] = make_float4(ex.x, ex.y, ex.z, ex.w);
    sms[wid][lane] = (int)sidx;
    // parity gather: lane covers 8 dims, 2 edges per step
    int p = lane >> 5;
    int dL = lane & 31;
    int h = dL >> 3;
    float acc[8];
    #pragma unroll
    for (int i = 0; i < 8; i++) acc[i] = 0.f;
    for (int c0 = 0; c0 < degT; c0 += 8) {
        int sv[4]; float av[4];
        #pragma unroll
        for (int t = 0; t < 4; t++) {
            int ee = c0 + 2 * t + p;          // <= 55 always (c0 <= 48)
            sv[t] = sms[wid][ee];
            av[t] = sma[wid][ee * 4 + h];     // 0 for slots >= degT
        }
        uint4 hv[4];
        #pragma unroll
        for (int t = 0; t < 4; t++)
            hv[t] = *(const uint4*)&hb[(unsigned)sv[t] * 256 + dL * 8];
        #pragma unroll
        for (int t = 0; t < 4; t++) {
            float a = av[t];
            acc[0] += a * bflo(hv[t].x); acc[1] += a * bfhi(hv[t].x);
            acc[2] += a * bflo(hv[t].y); acc[3] += a * bfhi(hv[t].y);
            acc[4] += a * bflo(hv[t].z); acc[5] += a * bfhi(hv[t].z);
            acc[6] += a * bflo(hv[t].w); acc[7] += a * bfhi(hv[t].w);
        }
    }
    #pragma unroll
    for (int i = 0; i < 8; i++) acc[i] += __shfl_xor(acc[i], 32);
    float smh = h == 0 ? sm.x : h == 1 ? sm.y : h == 2 ? sm.z : sm.w;
    float invh = 1.f / (smh + 1e-16f);
    float4 bb0 = *(const float4*)&b1[dL * 8];
    float4 bb1 = *(const float4*)&b1[dL * 8 + 4];
    float r[8];
    r[0] = acc[0] * invh + bb0.x; r[1] = acc[1] * invh + bb0.y;
    r[2] = acc[2] * invh + bb0.z; r[3] = acc[3] * invh + bb0.w;
    r[4] = acc[4] * invh + bb1.x; r[5] = acc[5] * invh + bb1.y;
    r[6] = acc[6] * invh + bb1.z; r[7] = acc[7] * invh + bb1.w;
    #pragma unroll
    for (int i = 0; i < 8; i++)
        r[i] = r[i] > 0.f ? r[i] : (__expf(r[i]) - 1.f);
    if (p == 0) {
        uint4 pk;
        pk.x = pack_bf2(r[0], r[1]); pk.y = pack_bf2(r[2], r[3]);
        pk.z = pack_bf2(r[4], r[5]); pk.w = pack_bf2(r[6], r[7]);
        *(uint4*)&h1b[node * 256 + dL * 8] = pk;
    }
}

// ------- K4: MFMA bf16 gemm2: h2 = h1 @ W2 + fused s2/d2 ---------------------
__global__ __launch_bounds__(256) void k_gemm2(const unsigned short* __restrict__ h1b,
        const unsigned short* __restrict__ wt2b, const float* __restrict__ as2,
        const float* __restrict__ ad2, float* __restrict__ h2,
        float* __restrict__ s2, float* __restrict__ d2, int M) {
    __shared__ unsigned short h1s[64 * LDK2];
    __shared__ unsigned short w2s[32 * LDK2];
    int tid = threadIdx.x;
    int bm = blockIdx.x * 64;
    #pragma unroll
    for (int i = 0; i < 8; i++) {
        int c = tid + i * 256;
        int row = c >> 5, off = (c & 31) * 8;
        int grow = bm + row;
        uint4 v = make_uint4(0u, 0u, 0u, 0u);
        if (grow < M) v = *(const uint4*)&h1b[grow * 256 + off];
        *(uint4*)&h1s[row * LDK2 + off] = v;
    }
    #pragma unroll
    for (int i = 0; i < 4; i++) {
        int c = tid + i * 256;
        int row = c >> 5, off = (c & 31) * 8;
        uint4 v = *(const uint4*)&wt2b[row * 256 + off];
        *(uint4*)&w2s[row * LDK2 + off] = v;
    }
    __syncthreads();

    int w = tid >> 6;
    int l = tid & 63;
    int l15 = l & 15, lg = l >> 4;

    f32x4 acc0 = (f32x4){0.f, 0.f, 0.f, 0.f};
    f32x4 acc1 = (f32x4){0.f, 0.f, 0.f, 0.f};
    #pragma unroll
    for (int ks = 0; ks < 8; ks++) {
        int k0 = ks * 32 + lg * 8;
        bf16x8 a = *(const bf16x8*)&h1s[(w * 16 + l15) * LDK2 + k0];
        bf16x8 b0 = *(const bf16x8*)&w2s[(l15) * LDK2 + k0];
        bf16x8 b1 = *(const bf16x8*)&w2s[(16 + l15) * LDK2 + k0];
        acc0 = __builtin_amdgcn_mfma_f32_16x16x32_bf16(a, b0, acc0, 0, 0, 0);
        acc1 = __builtin_amdgcn_mfma_f32_16x16x32_bf16(a, b1, acc1, 0, 0, 0);
    }

    #pragma unroll
    for (int r = 0; r < 4; r++) {
        int grow = bm + w * 16 + lg * 4 + r;
        if (grow < M) {
            h2[grow * 32 + l15] = acc0[r];
            h2[grow * 32 + 16 + l15] = acc1[r];
        }
    }
    float sc0 = as2[l15], sc1 = as2[16 + l15];
    float dc0 = ad2[l15], dc1 = ad2[16 + l15];
    #pragma unroll
    for (int r = 0; r < 4; r++) {
        float sp = acc0[r] * sc0 + acc1[r] * sc1;
        float dp = acc0[r] * dc0 + acc1[r] * dc1;
        #pragma unroll
        for (int o = 1; o < 16; o <<= 1) {
            sp += __shfl_xor(sp, o);
            dp += __shfl_xor(dp, o);
        }
        if (l15 == 0) {
            int grow = bm + w * 16 + lg * 4 + r;
            if (grow < M) { s2[grow] = sp; d2[grow] = dp; }
        }
    }
}

// ------- K5: FUSED layer-2 attention + agg -> z ------------------------------
__global__ __launch_bounds__(256) void k_agg2(const int* __restrict__ fill,
        const unsigned int* __restrict__ er, const float* __restrict__ s2,
        const float* __restrict__ d2, const float* __restrict__ scal,
        const float* __restrict__ h2, const float* __restrict__ b2,
        float* __restrict__ zout, int N) {
    __shared__ float sa2[4][64];
    __shared__ int   ss2[4][64];
    int wid = threadIdx.x >> 6;
    int node = blockIdx.x * 4 + wid;
    if (node >= N) return;
    int lane = threadIdx.x & 63;
    int deg = fill[node]; if (deg > CAP - 1) deg = CAP - 1;
    float dn = d2[node];
    float ce = scal[8], cc = scal[9];

    unsigned int rec = (unsigned int)node << 15;
    if (lane < deg) rec = er[node * CAP + lane];
    unsigned int sidx = rec >> 15;
    float ev = (float)(rec & 32767u) * (LN2V / EAQ);
    if (lane >= deg) ev = 0.f;
    float evm = wsum64(ev) / fmaxf((float)deg, 1.f);
    int degT = deg + 1;
    if (lane == deg) ev = evm;
    bool valid = lane < degT;

    float l = -1e30f;
    if (valid) {
        l = s2[sidx] + dn + ev * ce + cc;
        l = l > 0.f ? l : NEG_SLOPE * l;
    }
    float mx = l;
    #pragma unroll
    for (int o = 32; o; o >>= 1) mx = fmaxf(mx, __shfl_xor(mx, o));
    float ex = valid ? __expf(l - mx) : 0.f;
    float sm = wsum64(ex);
    float inv = 1.f / (sm + 1e-16f);
    sa2[wid][lane] = ex;          // 0 for invalid slots
    ss2[wid][lane] = (int)sidx;
    int p8 = lane >> 3, dL2 = lane & 7;   // 8 edges per step, 4 dims/lane
    float4 acc = make_float4(0.f, 0.f, 0.f, 0.f);
    for (int c0 = 0; c0 < degT; c0 += 32) {
        int sv[4]; float av[4];
        #pragma unroll
        for (int t = 0; t < 4; t++) {
            int ee = c0 + 8 * t + p8;     // <= 63 always
            sv[t] = ss2[wid][ee];
            av[t] = sa2[wid][ee];
        }
        float4 hv[4];
        #pragma unroll
        for (int t = 0; t < 4; t++)
            hv[t] = *(const float4*)&h2[(unsigned)sv[t] * 32 + dL2 * 4];
        #pragma unroll
        for (int t = 0; t < 4; t++) {
            acc.x += av[t] * hv[t].x; acc.y += av[t] * hv[t].y;
            acc.z += av[t] * hv[t].z; acc.w += av[t] * hv[t].w;
        }
    }
    #pragma unroll
    for (int o = 8; o <= 32; o <<= 1) {
        acc.x += __shfl_xor(acc.x, o); acc.y += __shfl_xor(acc.y, o);
        acc.z += __shfl_xor(acc.z, o); acc.w += __shfl_xor(acc.w, o);
    }
    if (lane < 8) {
        float4 bb = *(const float4*)&b2[dL2 * 4];
        float4 oo;
        oo.x = acc.x * inv + bb.x; oo.y = acc.y * inv + bb.y;
        oo.z = acc.z * inv + bb.z; oo.w = acc.w * inv + bb.w;
        *(float4*)&zout[node * 32 + dL2 * 4] = oo;
    }
}

// ---------------- K6: decoder MLP (fused 2 layers) ---------------------------
__global__ __launch_bounds__(256) void k_decoder(const float* __restrict__ z,
        const float* __restrict__ W1, const float* __restrict__ b1,
        const float* __restrict__ W2, const float* __restrict__ b2,
        float* __restrict__ xhat, int M) {
    __shared__ float zs[16][32];
    __shared__ float w1s[32 * 64];
    __shared__ float hid[16][68];
    __shared__ float w2s[64 * 128];
    int tid = threadIdx.x;
    int bn = blockIdx.x * 16;
    #pragma unroll
    for (int i = 0; i < 2; i++) {
        int idx = tid + i * 256;
        int r = idx >> 5, c = idx & 31;
        int row = bn + r;
        zs[r][c] = (row < M) ? z[row * 32 + c] : 0.f;
    }
    #pragma unroll
    for (int i = 0; i < 2; i++) {
        int idx = tid + i * 256;
        int r = idx >> 4, c = (idx & 15) * 4;
        *(float4*)&w1s[r * 64 + c] = *(const float4*)&W1[r * 64 + c];
    }
    #pragma unroll
    for (int i = 0; i < 8; i++) {
        int idx = tid + i * 256;
        int r = idx >> 5, c = (idx & 31) * 4;
        *(float4*)&w2s[r * 128 + c] = *(const float4*)&W2[r * 128 + c];
    }
    __syncthreads();
    {
        int nl = tid >> 4, c0 = (tid & 15) * 4;
        float4 acc = make_float4(0.f, 0.f, 0.f, 0.f);
        #pragma unroll 8
        for (int k = 0; k < 32; k++) {
            float zv = zs[nl][k];
            float4 w = *(float4*)&w1s[k * 64 + c0];
            acc.x += zv * w.x; acc.y += zv * w.y;
            acc.z += zv * w.z; acc.w += zv * w.w;
        }
        float4 bb = *(const float4*)&b1[c0];
        float r0 = acc.x + bb.x, r1 = acc.y + bb.y, r2 = acc.z + bb.z, r3 = acc.w + bb.w;
        r0 = r0 > 0.f ? r0 : (__expf(r0) - 1.f);
        r1 = r1 > 0.f ? r1 : (__expf(r1) - 1.f);
        r2 = r2 > 0.f ? r2 : (__expf(r2) - 1.f);
        r3 = r3 > 0.f ? r3 : (__expf(r3) - 1.f);
        hid[nl][c0] = r0; hid[nl][c0 + 1] = r1; hid[nl][c0 + 2] = r2; hid[nl][c0 + 3] = r3;
    }
    __syncthreads();
    {
        int nl = tid >> 4, c0 = (tid & 15) * 4;
        float acc[8];
        #pragma unroll
        for (int q = 0; q < 8; q++) acc[q] = 0.f;
        #pragma unroll 8
        for (int k = 0; k < 64; k++) {
            float hv = hid[nl][k];
            float4 w0 = *(float4*)&w2s[k * 128 + c0];
            float4 w1 = *(float4*)&w2s[k * 128 + c0 + 64];
            acc[0] += hv * w0.x; acc[1] += hv * w0.y; acc[2] += hv * w0.z; acc[3] += hv * w0.w;
            acc[4] += hv * w1.x; acc[5] += hv * w1.y; acc[6] += hv * w1.z; acc[7] += hv * w1.w;
        }
        int row = bn + nl;
        if (row < M) {
            float4 bb0 = *(const float4*)&b2[c0];
            float4 bb1 = *(const float4*)&b2[c0 + 64];
            float4 o0 = make_float4(acc[0] + bb0.x, acc[1] + bb0.y, acc[2] + bb0.z, acc[3] + bb0.w);
            float4 o1 = make_float4(acc[4] + bb1.x, acc[5] + bb1.y, acc[6] + bb1.z, acc[7] + bb1.w);
            *(float4*)&xhat[row * 128 + c0] = o0;
            *(float4*)&xhat[row * 128 + c0 + 64] = o1;
        }
    }
}

// ---------------- launch -----------------------------------------------------
extern "C" void kernel_launch(void* const* d_in, const int* in_sizes, int n_in,
                              void* d_out, int out_size, void* d_ws, size_t ws_size,
                              hipStream_t stream) {
    const float* x        = (const float*)d_in[0];
    const float* eattr    = (const float*)d_in[1];
    const float* bn_gamma = (const float*)d_in[2];
    const float* bn_beta  = (const float*)d_in[3];
    const float* W1       = (const float*)d_in[4];
    const float* We1      = (const float*)d_in[5];
    const float* as1      = (const float*)d_in[6];
    const float* ad1      = (const float*)d_in[7];
    const float* ae1      = (const float*)d_in[8];
    const float* b1       = (const float*)d_in[9];
    const float* W2       = (const float*)d_in[10];
    const float* We2      = (const float*)d_in[11];
    const float* as2      = (const float*)d_in[12];
    const float* ad2      = (const float*)d_in[13];
    const float* ae2      = (const float*)d_in[14];
    const float* b2       = (const float*)d_in[15];
    const float* dW1      = (const float*)d_in[16];
    const float* db1      = (const float*)d_in[17];
    const float* dW2      = (const float*)d_in[18];
    const float* db2      = (const float*)d_in[19];
    const int*   eidx     = (const int*)d_in[20];
    const int* src = eidx;
    const int* dst = eidx + EE;

    float* ws = (float*)d_ws;
    int*   fill = (int*)(ws + I_FILL);
    float* part = ws + F_PART;
    float* scal = ws + F_SCAL;
    unsigned short* wtb  = (unsigned short*)(ws + F_WTB);
    unsigned short* wt2b = (unsigned short*)(ws + F_WT2B);
    unsigned short* hb   = (unsigned short*)(ws + F_HB);
    float* s1   = ws + F_S1;
    float* d1   = ws + F_D1;
    unsigned short* h1b = (unsigned short*)(ws + F_H1B);
    float* h2   = ws + F_H2;
    float* s2   = ws + F_S2;
    float* d2   = ws + F_D2;
    unsigned int* er = (unsigned int*)(ws + I_ER);

    float* zout = (float*)d_out;               // N x 32
    float* xhat = (float*)d_out + NN * 32;     // N x 128

    k_prepw<<<160, 256, 0, stream>>>(W1, W2, wtb, wt2b, fill);
    k_scat_gemm<<<NPB + NGB, 256, 0, stream>>>(src, dst, eattr, fill, er, part,
                                               x, wtb, as1, ad1, hb, s1, d1, EE, NN);
    k_bn_final<<<1, 512, 0, stream>>>(part, bn_gamma, bn_beta, We1, ae1, We2, ae2, scal, EE);
    k_agg1<<<(NN + 3) / 4, 256, 0, stream>>>(fill, er, s1, d1, scal, hb, b1, h1b, NN);
    k_gemm2<<<(NN + 63) / 64, 256, 0, stream>>>(h1b, wt2b, as2, ad2, h2, s2, d2, NN);
    k_agg2<<<(NN + 3) / 4, 256, 0, stream>>>(fill, er, s2, d2, scal, h2, b2, zout, NN);
    k_decoder<<<(NN + 15) / 16, 256, 0, stream>>>(zout, dW1, db1, dW2, db2, xhat, NN);
}

// Round 17
// 130.190 us; speedup vs baseline: 1.0618x; 1.0618x over previous
//
#include <hip/hip_runtime.h>
#include <math.h>

#define NN 30000
#define EE 480000
#define NEG_SLOPE 0.2f
#define LDK 136          // gemm1 LDS K-stride (bf16 elems)
#define LDK2 264         // gemm2 LDS K-stride (bf16 elems)
#define CAP 48           // bucket capacity: 192 B = exactly 3 cache lines
#define NWIN 235         // ceil(EE/2048) edge windows
#define NPB8 (NWIN * 8)  // scatter blocks (window x 8 XCD slices)
#define NGB 938          // gemm1 blocks (ceil(NN/32))
#define EAQ 32767.0f
#define LN2V 0.6931472f
#define FILL_IDX(d) (((d) & 7) * 3750 + ((d) >> 3))   // XCD-exclusive counter lines

// ---------------- workspace layout (float units)
static const size_t I_FILL  = 0;          // NN ints (permuted index)
static const size_t F_PART  = 30000;      // 4096 (covers NPB8*2=3760)
static const size_t F_SCAL  = 34096;      // 16
static const size_t F_WTB   = 34112;      // W1^T bf16 [256][128]
static const size_t F_WT2B  = 50496;      // W2^T bf16 [32][256]
static const size_t F_HB    = 54592;      // NN*256 ushorts (bf16 h)
static const size_t F_S1    = 3894592;    // NN*4
static const size_t F_D1    = 4014592;    // NN*4
static const size_t F_H1B   = 4134592;    // NN*256 ushorts (bf16 h1)
static const size_t F_H2    = 7974592;    // NN*32
static const size_t F_S2    = 8934592;    // NN
static const size_t F_D2    = 8964592;    // NN
static const size_t I_ER    = 8994592;    // NN*48 uint (src<<15 | ea_q15)

typedef __attribute__((ext_vector_type(4))) float f32x4;
typedef __attribute__((ext_vector_type(8))) short bf16x8;

__device__ __forceinline__ float wsum64(float v) {
    #pragma unroll
    for (int o = 32; o; o >>= 1) v += __shfl_xor(v, o);
    return v;
}
__device__ __forceinline__ unsigned int pack_bf2(float a, float b) {
    unsigned int ua = __float_as_uint(a);
    unsigned int ub = __float_as_uint(b);
    ua = (ua + 0x7FFFu + ((ua >> 16) & 1u)) >> 16;
    ub = (ub + 0x7FFFu + ((ub >> 16) & 1u)) & 0xFFFF0000u;
    return ua | ub;
}
__device__ __forceinline__ unsigned short bf16r(float f) {
    unsigned int u = __float_as_uint(f);
    u = (u + 0x7FFFu + ((u >> 16) & 1u)) >> 16;
    return (unsigned short)u;
}
__device__ __forceinline__ float bflo(unsigned int u) { return __uint_as_float(u << 16); }
__device__ __forceinline__ float bfhi(unsigned int u) { return __uint_as_float(u & 0xFFFF0000u); }

// ---- K0: convert/transpose W1/W2 to bf16 + zero fill ------------------------
__global__ __launch_bounds__(256) void k_prepw(const float* __restrict__ W1,
        const float* __restrict__ W2, unsigned short* __restrict__ wtb,
        unsigned short* __restrict__ wt2b, int* __restrict__ fill) {
    int idx = blockIdx.x * 256 + threadIdx.x;
    if (idx < NN) fill[idx] = 0;
    if (idx < 128 * 256) {
        int k = idx >> 8, n = idx & 255;
        wtb[n * 128 + k] = bf16r(W1[idx]);
    } else if (idx < 128 * 256 + 256 * 32) {
        int i2 = idx - 128 * 256;
        int k = i2 >> 5, c = i2 & 31;
        wt2b[c * 256 + k] = bf16r(W2[i2]);
    }
}

// ---- K1: FUSED XCD-partitioned scatter (blocks [0,NPB8)) || gemm1 -----------
// Scatter: block (window w, xcd x=blk&7) handles edges in window w with
// dst&7==x. With round-robin blockIdx->XCD, each er line (bucket = 3 exact
// lines) and each fill counter line is written by ONE XCD only -> no RMW
// ping-pong. BN partial sums cover matched edges (each edge matched once).
__global__ __launch_bounds__(256) void k_scat_gemm(const int* __restrict__ src,
        const int* __restrict__ dst, const float* __restrict__ eattr,
        int* __restrict__ fill, unsigned int* __restrict__ er,
        float* __restrict__ part,
        const float* __restrict__ x, const unsigned short* __restrict__ wtb,
        const float* __restrict__ as1, const float* __restrict__ ad1,
        unsigned short* __restrict__ hb, float* __restrict__ s1,
        float* __restrict__ d1, int E, int M) {
    __shared__ char shbuf[32 * LDK * 2];   // 8704 B, shared by both paths
    int tid = threadIdx.x;

    if (blockIdx.x < NPB8) {
        // ================= scatter path =================
        float* sa = (float*)shbuf;
        float* sb = sa + 256;
        int window = blockIdx.x >> 3;
        int xcd = blockIdx.x & 7;
        int base = window * 2048;
        float s = 0.f, s2 = 0.f;
        #pragma unroll
        for (int t = 0; t < 8; t++) {
            int e = base + t * 256 + tid;
            if (e < E) {
                int d = dst[e];
                if ((d & 7) == xcd) {
                    float lv = log1pf(eattr[e]);
                    s += lv; s2 += lv * lv;
                    int pos = atomicAdd(&fill[FILL_IDX(d)], 1);
                    if (pos > CAP - 2) pos = CAP - 2;   // safety clamp
                    unsigned int q = (unsigned int)(lv * (EAQ / LN2V) + 0.5f);
                    if (q > 32767u) q = 32767u;
                    er[d * CAP + pos] = ((unsigned int)src[e] << 15) | q;
                }
            }
        }
        sa[tid] = s; sb[tid] = s2;
        __syncthreads();
        for (int o = 128; o; o >>= 1) {
            if (tid < o) { sa[tid] += sa[tid + o]; sb[tid] += sb[tid + o]; }
            __syncthreads();
        }
        if (tid == 0) { part[blockIdx.x * 2] = sa[0]; part[blockIdx.x * 2 + 1] = sb[0]; }
        return;
    }

    // ================= gemm1 path =================
    unsigned short* xs = (unsigned short*)shbuf;    // 32 x LDK bf16
    int bm = (blockIdx.x - NPB8) * 32;
    #pragma unroll
    for (int i = 0; i < 4; i++) {
        int idx = tid + i * 256;
        int row = idx >> 5, c4 = (idx & 31) * 4;
        int grow = bm + row;
        float4 v = make_float4(0.f, 0.f, 0.f, 0.f);
        if (grow < M) v = *(const float4*)&x[grow * 128 + c4];
        uint2 p = make_uint2(pack_bf2(v.x, v.y), pack_bf2(v.z, v.w));
        *(uint2*)&xs[row * LDK + c4] = p;
    }
    __syncthreads();

    int w = tid >> 6;
    int l = tid & 63;
    int l15 = l & 15, lg = l >> 4;

    f32x4 acc[2][4];
    #pragma unroll
    for (int m = 0; m < 2; m++)
        #pragma unroll
        for (int n = 0; n < 4; n++) acc[m][n] = (f32x4){0.f, 0.f, 0.f, 0.f};

    #pragma unroll
    for (int ks = 0; ks < 4; ks++) {
        int k0 = ks * 32 + lg * 8;
        bf16x8 a0 = *(const bf16x8*)&xs[(l15) * LDK + k0];
        bf16x8 a1 = *(const bf16x8*)&xs[(16 + l15) * LDK + k0];
        bf16x8 b[4];
        #pragma unroll
        for (int n = 0; n < 4; n++)
            b[n] = *(const bf16x8*)&wtb[(w * 64 + n * 16 + l15) * 128 + k0];
        #pragma unroll
        for (int n = 0; n < 4; n++) {
            acc[0][n] = __builtin_amdgcn_mfma_f32_16x16x32_bf16(a0, b[n], acc[0][n], 0, 0, 0);
            acc[1][n] = __builtin_amdgcn_mfma_f32_16x16x32_bf16(a1, b[n], acc[1][n], 0, 0, 0);
        }
    }

    #pragma unroll
    for (int m = 0; m < 2; m++) {
        #pragma unroll
        for (int r = 0; r < 4; r++) {
            int grow = bm + m * 16 + lg * 4 + r;
            if (grow < M) {
                #pragma unroll
                for (int n = 0; n < 4; n++)
                    hb[grow * 256 + w * 64 + n * 16 + l15] = bf16r(acc[m][n][r]);
            }
        }
    }
    float as_c[4], ad_c[4];
    #pragma unroll
    for (int n = 0; n < 4; n++) {
        as_c[n] = as1[w * 64 + n * 16 + l15];
        ad_c[n] = ad1[w * 64 + n * 16 + l15];
    }
    float sp[2][4], dp[2][4];
    #pragma unroll
    for (int m = 0; m < 2; m++)
        #pragma unroll
        for (int r = 0; r < 4; r++) {
            float s = 0.f, d = 0.f;
            #pragma unroll
            for (int n = 0; n < 4; n++) {
                s += acc[m][n][r] * as_c[n];
                d += acc[m][n][r] * ad_c[n];
            }
            sp[m][r] = s; dp[m][r] = d;
        }
    #pragma unroll
    for (int o = 1; o < 16; o <<= 1) {
        #pragma unroll
        for (int m = 0; m < 2; m++)
            #pragma unroll
            for (int r = 0; r < 4; r++) {
                sp[m][r] += __shfl_xor(sp[m][r], o);
                dp[m][r] += __shfl_xor(dp[m][r], o);
            }
    }
    if (l15 == 0) {
        #pragma unroll
        for (int m = 0; m < 2; m++)
            #pragma unroll
            for (int r = 0; r < 4; r++) {
                int grow = bm + m * 16 + lg * 4 + r;
                if (grow < M) {
                    s1[grow * 4 + w] = sp[m][r];
                    d1[grow * 4 + w] = dp[m][r];
                }
            }
    }
}

// ---- K2: finalize BN + folded attention edge constants ----------------------
__global__ __launch_bounds__(512) void k_bn_final(const float* __restrict__ part,
        const float* __restrict__ gamma, const float* __restrict__ beta,
        const float* __restrict__ We1, const float* __restrict__ ae1,
        const float* __restrict__ We2, const float* __restrict__ ae2,
        float* __restrict__ scal, int E) {
    __shared__ float sa[512], sb[512], sc[256];
    int tid = threadIdx.x;
    float s = 0.f, s2 = 0.f;
    for (int i = tid; i < NPB8; i += 512) {
        s += part[2 * i]; s2 += part[2 * i + 1];
    }
    sa[tid] = s; sb[tid] = s2;
    if (tid < 256) sc[tid] = We1[tid] * ae1[tid];
    __syncthreads();
    for (int o = 256; o; o >>= 1) {
        if (tid < o) { sa[tid] += sa[tid + o]; sb[tid] += sb[tid + o]; }
        __syncthreads();
    }
    if (tid == 0) {
        float mu = sa[0] / (float)E;
        float var = sb[0] / (float)E - mu * mu;
        float kA = gamma[0] / sqrtf(var + 1e-5f);
        float kB = beta[0] - mu * kA;
        for (int h = 0; h < 4; h++) {
            float s1 = 0.f;
            for (int d = 0; d < 64; d++) s1 += sc[h * 64 + d];
            scal[4 + h] = kA * s1;
            scal[10 + h] = kB * s1;
        }
        float s22 = 0.f;
        for (int d = 0; d < 32; d++) s22 += We2[d] * ae2[d];
        scal[8] = kA * s22;
        scal[9] = kB * s22;
    }
}

// ------- K3: FUSED layer-1 attention + aggregation ---------------------------
__global__ __launch_bounds__(256) void k_agg1(const int* __restrict__ fill,
        const unsigned int* __restrict__ er, const float* __restrict__ s1,
        const float* __restrict__ d1, const float* __restrict__ scal,
        const unsigned short* __restrict__ hb, const float* __restrict__ b1,
        unsigned short* __restrict__ h1b, int N) {
    __shared__ float sma[4][256];   // per-wave alpha table [edge][head]
    __shared__ int   sms[4][64];    // per-wave src table
    int wid = threadIdx.x >> 6;
    int node = blockIdx.x * 4 + wid;
    if (node >= N) return;
    int lane = threadIdx.x & 63;
    int deg = fill[FILL_IDX(node)]; if (deg > CAP - 1) deg = CAP - 1;
    float4 dv = *(const float4*)&d1[node * 4];
    float4 ce = *(const float4*)&scal[4];
    float4 cc = *(const float4*)&scal[10];

    // load packed record; lane >= deg defaults to (node, 0)
    unsigned int rec = (unsigned int)node << 15;
    if (lane < deg) rec = er[node * CAP + lane];
    unsigned int sidx = rec >> 15;
    float ev = (float)(rec & 32767u) * (LN2V / EAQ);
    if (lane >= deg) ev = 0.f;
    float evm = wsum64(ev) / fmaxf((float)deg, 1.f);   // self-loop raw mean
    int degT = deg + 1;
    if (lane == deg) ev = evm;
    bool valid = lane < degT;

    float4 l = make_float4(-1e30f, -1e30f, -1e30f, -1e30f);
    if (valid) {
        float4 sv = *(const float4*)&s1[sidx * 4];
        l.x = sv.x + dv.x + ev * ce.x + cc.x;
        l.y = sv.y + dv.y + ev * ce.y + cc.y;
        l.z = sv.z + dv.z + ev * ce.z + cc.z;
        l.w = sv.w + dv.w + ev * ce.w + cc.w;
        l.x = l.x > 0.f ? l.x : NEG_SLOPE * l.x;
        l.y = l.y > 0.f ? l.y : NEG_SLOPE * l.y;
        l.z = l.z > 0.f ? l.z : NEG_SLOPE * l.z;
        l.w = l.w > 0.f ? l.w : NEG_SLOPE * l.w;
    }
    float4 mx = l;
    #pragma unroll
    for (int o = 32; o; o >>= 1) {
        mx.x = fmaxf(mx.x, __shfl_xor(mx.x, o));
        mx.y = fmaxf(mx.y, __shfl_xor(mx.y, o));
        mx.z = fmaxf(mx.z, __shfl_xor(mx.z, o));
        mx.w = fmaxf(mx.w, __shfl_xor(mx.w, o));
    }
    float4 ex = make_float4(0.f, 0.f, 0.f, 0.f);
    if (valid) {
        ex.x = __expf(l.x - mx.x); ex.y = __expf(l.y - mx.y);
        ex.z = __expf(l.z - mx.z); ex.w = __expf(l.w - mx.w);
    }
    float4 sm = ex;
    #pragma unroll
    for (int o = 32; o; o >>= 1) {
        sm.x += __shfl_xor(sm.x, o); sm.y += __shfl_xor(sm.y, o);
        sm.z += __shfl_xor(sm.z, o); sm.w += __shfl_xor(sm.w, o);
    }
    // publish (alpha, src) to wave-private LDS (zeros for invalid)
    *(float4*)&sma[wid][lane * 4] = make_float4(ex.x, ex.y, ex.z, ex.w);
    sms[wid][lane] = (int)sidx;
    // parity gather: lane covers 8 dims, 2 edges per step
    int p = lane >> 5;
    int dL = lane & 31;
    int h = dL >> 3;
    float acc[8];
    #pragma unroll
    for (int i = 0; i < 8; i++) acc[i] = 0.f;
    for (int c0 = 0; c0 < degT; c0 += 8) {
        int sv[4]; float av[4];
        #pragma unroll
        for (int t = 0; t < 4; t++) {
            int ee = c0 + 2 * t + p;          // <= 55 always (c0 <= 48)
            sv[t] = sms[wid][ee];
            av[t] = sma[wid][ee * 4 + h];     // 0 for slots >= degT
        }
        uint4 hv[4];
        #pragma unroll
        for (int t = 0; t < 4; t++)
            hv[t] = *(const uint4*)&hb[(unsigned)sv[t] * 256 + dL * 8];
        #pragma unroll
        for (int t = 0; t < 4; t++) {
            float a = av[t];
            acc[0] += a * bflo(hv[t].x); acc[1] += a * bfhi(hv[t].x);
            acc[2] += a * bflo(hv[t].y); acc[3] += a * bfhi(hv[t].y);
            acc[4] += a * bflo(hv[t].z); acc[5] += a * bfhi(hv[t].z);
            acc[6] += a * bflo(hv[t].w); acc[7] += a * bfhi(hv[t].w);
        }
    }
    #pragma unroll
    for (int i = 0; i < 8; i++) acc[i] += __shfl_xor(acc[i], 32);
    float smh = h == 0 ? sm.x : h == 1 ? sm.y : h == 2 ? sm.z : sm.w;
    float invh = 1.f / (smh + 1e-16f);
    float4 bb0 = *(const float4*)&b1[dL * 8];
    float4 bb1 = *(const float4*)&b1[dL * 8 + 4];
    float r[8];
    r[0] = acc[0] * invh + bb0.x; r[1] = acc[1] * invh + bb0.y;
    r[2] = acc[2] * invh + bb0.z; r[3] = acc[3] * invh + bb0.w;
    r[4] = acc[4] * invh + bb1.x; r[5] = acc[5] * invh + bb1.y;
    r[6] = acc[6] * invh + bb1.z; r[7] = acc[7] * invh + bb1.w;
    #pragma unroll
    for (int i = 0; i < 8; i++)
        r[i] = r[i] > 0.f ? r[i] : (__expf(r[i]) - 1.f);
    if (p == 0) {
        uint4 pk;
        pk.x = pack_bf2(r[0], r[1]); pk.y = pack_bf2(r[2], r[3]);
        pk.z = pack_bf2(r[4], r[5]); pk.w = pack_bf2(r[6], r[7]);
        *(uint4*)&h1b[node * 256 + dL * 8] = pk;
    }
}

// ------- K4: MFMA bf16 gemm2: h2 = h1 @ W2 + fused s2/d2 ---------------------
__global__ __launch_bounds__(256) void k_gemm2(const unsigned short* __restrict__ h1b,
        const unsigned short* __restrict__ wt2b, const float* __restrict__ as2,
        const float* __restrict__ ad2, float* __restrict__ h2,
        float* __restrict__ s2, float* __restrict__ d2, int M) {
    __shared__ unsigned short h1s[64 * LDK2];
    __shared__ unsigned short w2s[32 * LDK2];
    int tid = threadIdx.x;
    int bm = blockIdx.x * 64;
    #pragma unroll
    for (int i = 0; i < 8; i++) {
        int c = tid + i * 256;
        int row = c >> 5, off = (c & 31) * 8;
        int grow = bm + row;
        uint4 v = make_uint4(0u, 0u, 0u, 0u);
        if (grow < M) v = *(const uint4*)&h1b[grow * 256 + off];
        *(uint4*)&h1s[row * LDK2 + off] = v;
    }
    #pragma unroll
    for (int i = 0; i < 4; i++) {
        int c = tid + i * 256;
        int row = c >> 5, off = (c & 31) * 8;
        uint4 v = *(const uint4*)&wt2b[row * 256 + off];
        *(uint4*)&w2s[row * LDK2 + off] = v;
    }
    __syncthreads();

    int w = tid >> 6;
    int l = tid & 63;
    int l15 = l & 15, lg = l >> 4;

    f32x4 acc0 = (f32x4){0.f, 0.f, 0.f, 0.f};
    f32x4 acc1 = (f32x4){0.f, 0.f, 0.f, 0.f};
    #pragma unroll
    for (int ks = 0; ks < 8; ks++) {
        int k0 = ks * 32 + lg * 8;
        bf16x8 a = *(const bf16x8*)&h1s[(w * 16 + l15) * LDK2 + k0];
        bf16x8 b0 = *(const bf16x8*)&w2s[(l15) * LDK2 + k0];
        bf16x8 b1 = *(const bf16x8*)&w2s[(16 + l15) * LDK2 + k0];
        acc0 = __builtin_amdgcn_mfma_f32_16x16x32_bf16(a, b0, acc0, 0, 0, 0);
        acc1 = __builtin_amdgcn_mfma_f32_16x16x32_bf16(a, b1, acc1, 0, 0, 0);
    }

    #pragma unroll
    for (int r = 0; r < 4; r++) {
        int grow = bm + w * 16 + lg * 4 + r;
        if (grow < M) {
            h2[grow * 32 + l15] = acc0[r];
            h2[grow * 32 + 16 + l15] = acc1[r];
        }
    }
    float sc0 = as2[l15], sc1 = as2[16 + l15];
    float dc0 = ad2[l15], dc1 = ad2[16 + l15];
    #pragma unroll
    for (int r = 0; r < 4; r++) {
        float sp = acc0[r] * sc0 + acc1[r] * sc1;
        float dp = acc0[r] * dc0 + acc1[r] * dc1;
        #pragma unroll
        for (int o = 1; o < 16; o <<= 1) {
            sp += __shfl_xor(sp, o);
            dp += __shfl_xor(dp, o);
        }
        if (l15 == 0) {
            int grow = bm + w * 16 + lg * 4 + r;
            if (grow < M) { s2[grow] = sp; d2[grow] = dp; }
        }
    }
}

// ------- K5: FUSED layer-2 attention + agg -> z ------------------------------
__global__ __launch_bounds__(256) void k_agg2(const int* __restrict__ fill,
        const unsigned int* __restrict__ er, const float* __restrict__ s2,
        const float* __restrict__ d2, const float* __restrict__ scal,
        const float* __restrict__ h2, const float* __restrict__ b2,
        float* __restrict__ zout, int N) {
    __shared__ float sa2[4][64];
    __shared__ int   ss2[4][64];
    int wid = threadIdx.x >> 6;
    int node = blockIdx.x * 4 + wid;
    if (node >= N) return;
    int lane = threadIdx.x & 63;
    int deg = fill[FILL_IDX(node)]; if (deg > CAP - 1) deg = CAP - 1;
    float dn = d2[node];
    float ce = scal[8], cc = scal[9];

    unsigned int rec = (unsigned int)node << 15;
    if (lane < deg) rec = er[node * CAP + lane];
    unsigned int sidx = rec >> 15;
    float ev = (float)(rec & 32767u) * (LN2V / EAQ);
    if (lane >= deg) ev = 0.f;
    float evm = wsum64(ev) / fmaxf((float)deg, 1.f);
    int degT = deg + 1;
    if (lane == deg) ev = evm;
    bool valid = lane < degT;

    float l = -1e30f;
    if (valid) {
        l = s2[sidx] + dn + ev * ce + cc;
        l = l > 0.f ? l : NEG_SLOPE * l;
    }
    float mx = l;
    #pragma unroll
    for (int o = 32; o; o >>= 1) mx = fmaxf(mx, __shfl_xor(mx, o));
    float ex = valid ? __expf(l - mx) : 0.f;
    float sm = wsum64(ex);
    float inv = 1.f / (sm + 1e-16f);
    sa2[wid][lane] = ex;          // 0 for invalid slots
    ss2[wid][lane] = (int)sidx;
    int p8 = lane >> 3, dL2 = lane & 7;   // 8 edges per step, 4 dims/lane
    float4 acc = make_float4(0.f, 0.f, 0.f, 0.f);
    for (int c0 = 0; c0 < degT; c0 += 32) {
        int sv[4]; float av[4];
        #pragma unroll
        for (int t = 0; t < 4; t++) {
            int ee = c0 + 8 * t + p8;     // <= 63 always
            sv[t] = ss2[wid][ee];
            av[t] = sa2[wid][ee];
        }
        float4 hv[4];
        #pragma unroll
        for (int t = 0; t < 4; t++)
            hv[t] = *(const float4*)&h2[(unsigned)sv[t] * 32 + dL2 * 4];
        #pragma unroll
        for (int t = 0; t < 4; t++) {
            acc.x += av[t] * hv[t].x; acc.y += av[t] * hv[t].y;
            acc.z += av[t] * hv[t].z; acc.w += av[t] * hv[t].w;
        }
    }
    #pragma unroll
    for (int o = 8; o <= 32; o <<= 1) {
        acc.x += __shfl_xor(acc.x, o); acc.y += __shfl_xor(acc.y, o);
        acc.z += __shfl_xor(acc.z, o); acc.w += __shfl_xor(acc.w, o);
    }
    if (lane < 8) {
        float4 bb = *(const float4*)&b2[dL2 * 4];
        float4 oo;
        oo.x = acc.x * inv + bb.x; oo.y = acc.y * inv + bb.y;
        oo.z = acc.z * inv + bb.z; oo.w = acc.w * inv + bb.w;
        *(float4*)&zout[node * 32 + dL2 * 4] = oo;
    }
}

// ---------------- K6: decoder MLP (fused 2 layers) ---------------------------
__global__ __launch_bounds__(256) void k_decoder(const float* __restrict__ z,
        const float* __restrict__ W1, const float* __restrict__ b1,
        const float* __restrict__ W2, const float* __restrict__ b2,
        float* __restrict__ xhat, int M) {
    __shared__ float zs[16][32];
    __shared__ float w1s[32 * 64];
    __shared__ float hid[16][68];
    __shared__ float w2s[64 * 128];
    int tid = threadIdx.x;
    int bn = blockIdx.x * 16;
    #pragma unroll
    for (int i = 0; i < 2; i++) {
        int idx = tid + i * 256;
        int r = idx >> 5, c = idx & 31;
        int row = bn + r;
        zs[r][c] = (row < M) ? z[row * 32 + c] : 0.f;
    }
    #pragma unroll
    for (int i = 0; i < 2; i++) {
        int idx = tid + i * 256;
        int r = idx >> 4, c = (idx & 15) * 4;
        *(float4*)&w1s[r * 64 + c] = *(const float4*)&W1[r * 64 + c];
    }
    #pragma unroll
    for (int i = 0; i < 8; i++) {
        int idx = tid + i * 256;
        int r = idx >> 5, c = (idx & 31) * 4;
        *(float4*)&w2s[r * 128 + c] = *(const float4*)&W2[r * 128 + c];
    }
    __syncthreads();
    {
        int nl = tid >> 4, c0 = (tid & 15) * 4;
        float4 acc = make_float4(0.f, 0.f, 0.f, 0.f);
        #pragma unroll 8
        for (int k = 0; k < 32; k++) {
            float zv = zs[nl][k];
            float4 w = *(float4*)&w1s[k * 64 + c0];
            acc.x += zv * w.x; acc.y += zv * w.y;
            acc.z += zv * w.z; acc.w += zv * w.w;
        }
        float4 bb = *(const float4*)&b1[c0];
        float r0 = acc.x + bb.x, r1 = acc.y + bb.y, r2 = acc.z + bb.z, r3 = acc.w + bb.w;
        r0 = r0 > 0.f ? r0 : (__expf(r0) - 1.f);
        r1 = r1 > 0.f ? r1 : (__expf(r1) - 1.f);
        r2 = r2 > 0.f ? r2 : (__expf(r2) - 1.f);
        r3 = r3 > 0.f ? r3 : (__expf(r3) - 1.f);
        hid[nl][c0] = r0; hid[nl][c0 + 1] = r1; hid[nl][c0 + 2] = r2; hid[nl][c0 + 3] = r3;
    }
    __syncthreads();
    {
        int nl = tid >> 4, c0 = (tid & 15) * 4;
        float acc[8];
        #pragma unroll
        for (int q = 0; q < 8; q++) acc[q] = 0.f;
        #pragma unroll 8
        for (int k = 0; k < 64; k++) {
            float hv = hid[nl][k];
            float4 w0 = *(float4*)&w2s[k * 128 + c0];
            float4 w1 = *(float4*)&w2s[k * 128 + c0 + 64];
            acc[0] += hv * w0.x; acc[1] += hv * w0.y; acc[2] += hv * w0.z; acc[3] += hv * w0.w;
            acc[4] += hv * w1.x; acc[5] += hv * w1.y; acc[6] += hv * w1.z; acc[7] += hv * w1.w;
        }
        int row = bn + nl;
        if (row < M) {
            float4 bb0 = *(const float4*)&b2[c0];
            float4 bb1 = *(const float4*)&b2[c0 + 64];
            float4 o0 = make_float4(acc[0] + bb0.x, acc[1] + bb0.y, acc[2] + bb0.z, acc[3] + bb0.w);
            float4 o1 = make_float4(acc[4] + bb1.x, acc[5] + bb1.y, acc[6] + bb1.z, acc[7] + bb1.w);
            *(float4*)&xhat[row * 128 + c0] = o0;
            *(float4*)&xhat[row * 128 + c0 + 64] = o1;
        }
    }
}

// ---------------- launch -----------------------------------------------------
extern "C" void kernel_launch(void* const* d_in, const int* in_sizes, int n_in,
                              void* d_out, int out_size, void* d_ws, size_t ws_size,
                              hipStream_t stream) {
    const float* x        = (const float*)d_in[0];
    const float* eattr    = (const float*)d_in[1];
    const float* bn_gamma = (const float*)d_in[2];
    const float* bn_beta  = (const float*)d_in[3];
    const float* W1       = (const float*)d_in[4];
    const float* We1      = (const float*)d_in[5];
    const float* as1      = (const float*)d_in[6];
    const float* ad1      = (const float*)d_in[7];
    const float* ae1      = (const float*)d_in[8];
    const float* b1       = (const float*)d_in[9];
    const float* W2       = (const float*)d_in[10];
    const float* We2      = (const float*)d_in[11];
    const float* as2      = (const float*)d_in[12];
    const float* ad2      = (const float*)d_in[13];
    const float* ae2      = (const float*)d_in[14];
    const float* b2       = (const float*)d_in[15];
    const float* dW1      = (const float*)d_in[16];
    const float* db1      = (const float*)d_in[17];
    const float* dW2      = (const float*)d_in[18];
    const float* db2      = (const float*)d_in[19];
    const int*   eidx     = (const int*)d_in[20];
    const int* src = eidx;
    const int* dst = eidx + EE;

    float* ws = (float*)d_ws;
    int*   fill = (int*)(ws + I_FILL);
    float* part = ws + F_PART;
    float* scal = ws + F_SCAL;
    unsigned short* wtb  = (unsigned short*)(ws + F_WTB);
    unsigned short* wt2b = (unsigned short*)(ws + F_WT2B);
    unsigned short* hb   = (unsigned short*)(ws + F_HB);
    float* s1   = ws + F_S1;
    float* d1   = ws + F_D1;
    unsigned short* h1b = (unsigned short*)(ws + F_H1B);
    float* h2   = ws + F_H2;
    float* s2   = ws + F_S2;
    float* d2   = ws + F_D2;
    unsigned int* er = (unsigned int*)(ws + I_ER);

    float* zout = (float*)d_out;               // N x 32
    float* xhat = (float*)d_out + NN * 32;     // N x 128

    k_prepw<<<160, 256, 0, stream>>>(W1, W2, wtb, wt2b, fill);
    k_scat_gemm<<<NPB8 + NGB, 256, 0, stream>>>(src, dst, eattr, fill, er, part,
                                                x, wtb, as1, ad1, hb, s1, d1, EE, NN);
    k_bn_final<<<1, 512, 0, stream>>>(part, bn_gamma, bn_beta, We1, ae1, We2, ae2, scal, EE);
    k_agg1<<<(NN + 3) / 4, 256, 0, stream>>>(fill, er, s1, d1, scal, hb, b1, h1b, NN);
    k_gemm2<<<(NN + 63) / 64, 256, 0, stream>>>(h1b, wt2b, as2, ad2, h2, s2, d2, NN);
    k_agg2<<<(NN + 3) / 4, 256, 0, stream>>>(fill, er, s2, d2, scal, h2, b2, zout, NN);
    k_decoder<<<(NN + 15) / 16, 256, 0, stream>>>(zout, dW1, db1, dW2, db2, xhat, NN);
}